// Round 8
// baseline (413.400 us; speedup 1.0000x reference)
//
#include <hip/hip_runtime.h>
#include <hip/hip_bf16.h>

// Problem constants
#define BHALF 4096      // B = 8192/2
#define DDIM 128        // feature dim per matrix
#define KCAT 384        // 3*DDIM, packed row width
#define TEMP_INV 10.0f  // 1/TEMP
#define EXP2K 14.426950408889634f  // 10 * log2(e): exp(v*10) = exp2(v*EXP2K)

typedef __attribute__((ext_vector_type(8))) short short8;   // 8 bf16
typedef __attribute__((ext_vector_type(4))) float f32x4;    // 16x16 MFMA acc

// Async global->LDS, 16B per lane. LDS dest is wave-uniform base (HW adds
// lane*16). Global source is per-lane.
__device__ __forceinline__ void gload16(const ushort* g, ushort* l) {
  __builtin_amdgcn_global_load_lds(
      (const __attribute__((address_space(1))) unsigned int*)g,
      (__attribute__((address_space(3))) unsigned int*)l, 16, 0, 0);
}

// ---------------------------------------------------------------------------
// Fused normalize + diag: one wave per (matrix, row-pair i).
__global__ __launch_bounds__(256) void norm_diag_kernel(
    const float* __restrict__ x, const float* __restrict__ y,
    const float* __restrict__ z, ushort* __restrict__ nrm1,
    ushort* __restrict__ nrm2, float* __restrict__ dxyz) {
  int wave = threadIdx.x >> 6;
  int lane = threadIdx.x & 63;
  int gi = blockIdx.x * 4 + wave;  // 0 .. 3*4096-1
  int mat = gi >> 12;
  int i = gi & 4095;
  const float* src = (mat == 0 ? x : (mat == 1 ? y : z));
  float2 a = *(const float2*)(src + (size_t)i * DDIM + lane * 2);
  float2 b = *(const float2*)(src + (size_t)(i + BHALF) * DDIM + lane * 2);
  float s1 = a.x * a.x + a.y * a.y;
  float s2 = b.x * b.x + b.y * b.y;
  float d = a.x * b.x + a.y * b.y;
#pragma unroll
  for (int m = 1; m < 64; m <<= 1) {
    s1 += __shfl_xor(s1, m, 64);
    s2 += __shfl_xor(s2, m, 64);
    d += __shfl_xor(d, m, 64);
  }
  float r1 = 1.0f / fmaxf(sqrtf(s1), 1e-12f);
  float r2 = 1.0f / fmaxf(sqrtf(s2), 1e-12f);
  ushort* d1 = nrm1 + (size_t)i * KCAT + mat * DDIM + lane * 2;
  ushort* d2 = nrm2 + (size_t)i * KCAT + mat * DDIM + lane * 2;
  __hip_bfloat162 o1, o2;
  o1.x = __float2bfloat16(a.x * r1);
  o1.y = __float2bfloat16(a.y * r1);
  o2.x = __float2bfloat16(b.x * r2);
  o2.y = __float2bfloat16(b.y * r2);
  *(__hip_bfloat162*)d1 = o1;
  *(__hip_bfloat162*)d2 = o2;
  if (lane == 0) dxyz[mat * BHALF + i] = d * r1 * r2;
}

// ---------------------------------------------------------------------------
// Fused 4-gram kernel v4: 256x128 tile, 8 waves (4x2, wave tile 64x64),
// 16x16x32 bf16 MFMA, BK=32, 24 K-steps:
//   t 0-11 : g3^T = mfma(nrm2_frag, nrm1_frag), K=384 (swapped operands so
//            the needed reduction is the cheap lane-local direction)
//   t 12-15: g0 = x1·y1^T   t 16-19: g1 = x1·z1^T   t 20-23: g2 = y1·z1^T
// Double-buffered global_load_lds staging, counted vmcnt(3).
// KEY R8 changes vs R7:
//  - BK=32 -> 48 KB LDS buffers (+5.6 KB scratch) -> 2 blocks/CU resident
//    (implicit overlap fills barrier/latency stalls; R7 had 1 block/CU).
//  - NO global atomics in the K-loop: flushes reduce into LDS scratch via
//    ds_add_f32 (lgkm, invisible to vmcnt). R7's flush atomicAdds were VMEM
//    ops and the next vmcnt(6) drained ~80 contended atomics per wave.
//  - One epilogue pass does ~3 global atomics/thread.
// sums layout (4096 floats each): [rs0, cs0, rs1, cs1, rs2, cs2, rs3]
__global__ __launch_bounds__(512)
__attribute__((amdgpu_waves_per_eu(4))) void gram_fused_kernel(
    const ushort* __restrict__ nrm1, const ushort* __restrict__ nrm2,
    float* __restrict__ sums) {
  __shared__ ushort As[2 * 256 * 32];  // 32 KB: buf*8192 + row*32 + col
  __shared__ ushort Bs[2 * 128 * 32];  // 16 KB: buf*4096 + row*32 + col
  // Flush scratch: [0,256) g3 rows | [256,512) rs0 | [512,640) cs0 |
  // [640,896) rs1 | [896,1024) cs1 | [1024,1280) rs2 | [1280,1408) cs2
  __shared__ float fl[1408];

  int tid = threadIdx.x;
  int lane = tid & 63;
  int wave = tid >> 6;  // 0..7
  int wr = wave >> 1;   // 0..3: rows wr*64
  int wc = wave & 1;    // 0..1: cols wc*64

  int rowbase = blockIdx.x * 256;
  int colbase = blockIdx.y * 128;

  for (int i = tid; i < 1408; i += 512) fl[i] = 0.0f;

  // Staging: lane l -> row base+(l>>2), 16B chunk (l&3); source chunk
  // pre-swizzled by (l>>3)&3 (R2-verified 0-conflict involution).
  int srow = lane >> 2;
  int swz8 = ((lane & 3) ^ ((lane >> 3) & 3)) << 3;
  const ushort* gA =
      nrm1 + (size_t)(rowbase + wave * 32 + srow) * KCAT + swz8;
  const ushort* gB1 =
      nrm1 + (size_t)(colbase + wave * 16 + srow) * KCAT + swz8;
  const ushort* gB2 =
      nrm2 + (size_t)(colbase + wave * 16 + srow) * KCAT + swz8;

  // Fragment reads (R2-verified): row = grp*16 + rsel, k-chunk = lane>>4,
  // slot = chunk ^ ((rsel>>1)&3).
  int rsel = lane & 15;
  int slot8 = (((lane >> 4) ^ ((rsel >> 1) & 3)) << 3);

  f32x4 acc[4][4] = {};

  // In-LDS flush helpers (ds_add_f32 — never touches vmcnt).
  auto flush_cheap = [&]() {
#pragma unroll
    for (int m = 0; m < 4; ++m) {
      float s = 0.0f;
#pragma unroll
      for (int n = 0; n < 4; ++n)
#pragma unroll
        for (int r = 0; r < 4; ++r) s += exp2f(acc[m][n][r] * EXP2K);
      s += __shfl_xor(s, 16, 64);
      s += __shfl_xor(s, 32, 64);
      if (lane < 16) atomicAdd(&fl[wr * 64 + m * 16 + lane], s);
#pragma unroll
      for (int n = 0; n < 4; ++n)
#pragma unroll
        for (int r = 0; r < 4; ++r) acc[m][n][r] = 0.0f;
    }
  };
  auto flush_full = [&](int roff, int coff) {
#pragma unroll
    for (int m = 0; m < 4; ++m)
#pragma unroll
      for (int n = 0; n < 4; ++n)
#pragma unroll
        for (int r = 0; r < 4; ++r)
          acc[m][n][r] = exp2f(acc[m][n][r] * EXP2K);
    // row sums (reduce over cols: n + xor over lane&15)
#pragma unroll
    for (int m = 0; m < 4; ++m) {
      float rsum[4];
#pragma unroll
      for (int r = 0; r < 4; ++r)
        rsum[r] = acc[m][0][r] + acc[m][1][r] + acc[m][2][r] + acc[m][3][r];
#pragma unroll
      for (int r = 0; r < 4; ++r) {
        rsum[r] += __shfl_xor(rsum[r], 1, 64);
        rsum[r] += __shfl_xor(rsum[r], 2, 64);
        rsum[r] += __shfl_xor(rsum[r], 4, 64);
        rsum[r] += __shfl_xor(rsum[r], 8, 64);
      }
      if ((lane & 15) == 0) {
        int rb = roff + wr * 64 + m * 16 + (lane >> 4) * 4;
#pragma unroll
        for (int r = 0; r < 4; ++r) atomicAdd(&fl[rb + r], rsum[r]);
      }
    }
    // col sums (reduce over rows: m, r, xor16, xor32)
#pragma unroll
    for (int n = 0; n < 4; ++n) {
      float c = 0.0f;
#pragma unroll
      for (int m = 0; m < 4; ++m)
#pragma unroll
        for (int r = 0; r < 4; ++r) c += acc[m][n][r];
      c += __shfl_xor(c, 16, 64);
      c += __shfl_xor(c, 32, 64);
      if (lane < 16) atomicAdd(&fl[coff + wc * 64 + n * 16 + lane], c);
#pragma unroll
      for (int m = 0; m < 4; ++m)
#pragma unroll
        for (int r = 0; r < 4; ++r) acc[m][n][r] = 0.0f;
    }
  };

#define SCHED(t, ao, bp)                                                     \
  do {                                                                       \
    if ((t) < 12)      { ao = (t) * 32;            bp = gB2 + (t) * 32; }    \
    else if ((t) < 16) { ao = ((t)-12) * 32;       bp = gB1 + 128 + ((t)-12) * 32; } \
    else if ((t) < 20) { ao = ((t)-16) * 32;       bp = gB1 + 256 + ((t)-16) * 32; } \
    else               { ao = 128 + ((t)-20) * 32; bp = gB1 + 256 + ((t)-20) * 32; } \
  } while (0)

  // A: 2 loads (16 rows each), B: 1 load, per wave per step.
#define STAGE(b, ao, bp)                                                     \
  do {                                                                       \
    gload16(gA + (ao), &As[(b)*8192 + wave * 1024]);                         \
    gload16(gA + (ao) + (size_t)16 * KCAT, &As[(b)*8192 + wave * 1024 + 512]); \
    gload16((bp), &Bs[(b)*4096 + wave * 512]);                               \
  } while (0)

  {
    int ao; const ushort* bp;
    SCHED(0, ao, bp);
    STAGE(0, ao, bp);
  }

  int buf = 0;
  for (int gt = 0; gt < 24; ++gt) {
    if (gt < 23) {
      int ao; const ushort* bp;
      SCHED(gt + 1, ao, bp);
      STAGE(buf ^ 1, ao, bp);
      // wait only for this step's 3 loads; next step's 3 stay in flight
      asm volatile("s_waitcnt vmcnt(3)" ::: "memory");
    } else {
      asm volatile("s_waitcnt vmcnt(0)" ::: "memory");
    }
    __builtin_amdgcn_s_barrier();
    __builtin_amdgcn_sched_barrier(0);  // no LDS-read hoisting above barrier

    const ushort* A = &As[buf * 8192];
    const ushort* B = &Bs[buf * 4096];
    short8 af[4], bf[4];
#pragma unroll
    for (int m = 0; m < 4; ++m)
      af[m] = *(const short8*)&A[(wr * 64 + m * 16 + rsel) * 32 + slot8];
#pragma unroll
    for (int n = 0; n < 4; ++n)
      bf[n] = *(const short8*)&B[(wc * 64 + n * 16 + rsel) * 32 + slot8];
    if (gt < 12) {
#pragma unroll
      for (int m = 0; m < 4; ++m)
#pragma unroll
        for (int n = 0; n < 4; ++n)
          acc[m][n] = __builtin_amdgcn_mfma_f32_16x16x32_bf16(
              bf[n], af[m], acc[m][n], 0, 0, 0);
    } else {
#pragma unroll
      for (int m = 0; m < 4; ++m)
#pragma unroll
        for (int n = 0; n < 4; ++n)
          acc[m][n] = __builtin_amdgcn_mfma_f32_16x16x32_bf16(
              af[m], bf[n], acc[m][n], 0, 0, 0);
    }
    __builtin_amdgcn_s_barrier();  // buf reads done before its next overwrite

    if (gt == 11) flush_cheap();
    else if (gt == 15) flush_full(256, 512);
    else if (gt == 19) flush_full(640, 896);
    buf ^= 1;
  }
  flush_full(1024, 1280);
#undef STAGE
#undef SCHED

  // Epilogue: one coalesced global-atomic pass (~3 per thread).
  __syncthreads();
  for (int i = tid; i < 1408; i += 512) {
    float v = fl[i];
    float* dst;
    if (i < 256)       dst = &sums[6 * 4096 + rowbase + i];
    else if (i < 512)  dst = &sums[rowbase + i - 256];
    else if (i < 640)  dst = &sums[4096 + colbase + i - 512];
    else if (i < 896)  dst = &sums[2 * 4096 + rowbase + i - 640];
    else if (i < 1024) dst = &sums[3 * 4096 + colbase + i - 896];
    else if (i < 1280) dst = &sums[4 * 4096 + rowbase + i - 1024];
    else               dst = &sums[5 * 4096 + colbase + i - 1280];
    atomicAdd(dst, v);
  }
}

// ---------------------------------------------------------------------------
// Final scalar reduction.
__global__ __launch_bounds__(1024) void loss_kernel(
    const float* __restrict__ sums, const float* __restrict__ dxyz,
    float* __restrict__ out) {
  const float* rs0 = sums;
  const float* cs0 = sums + 4096;
  const float* rs1 = sums + 2 * 4096;
  const float* cs1 = sums + 3 * 4096;
  const float* rs2 = sums + 4 * 4096;
  const float* cs2 = sums + 5 * 4096;
  const float* rs3 = sums + 6 * 4096;
  int tid = threadIdx.x;
  float acc = 0.0f;
  for (int i = tid; i < BHALF; i += 1024) {
    float dxv = dxyz[i];
    float dyv = dxyz[4096 + i];
    float dzv = dxyz[2 * 4096 + i];
    float lx = logf(rs0[i] + rs1[i]) - TEMP_INV * dxv;
    float ly = logf(cs0[i] + rs2[i]) - TEMP_INV * dyv;
    float lz = logf(cs1[i] + cs2[i]) - TEMP_INV * dzv;
    float lv = logf(rs3[i]) - TEMP_INV * (dxv + dyv + dzv);
    acc += lx + ly + lz + lv;
  }
  __shared__ float red[16];
#pragma unroll
  for (int m = 1; m < 64; m <<= 1) acc += __shfl_xor(acc, m, 64);
  if ((tid & 63) == 0) red[tid >> 6] = acc;
  __syncthreads();
  if (tid == 0) {
    float t = 0.0f;
#pragma unroll
    for (int i = 0; i < 16; ++i) t += red[i];
    out[0] = t * (1.0f / 4096.0f);
  }
}

// ---------------------------------------------------------------------------
extern "C" void kernel_launch(void* const* d_in, const int* in_sizes, int n_in,
                              void* d_out, int out_size, void* d_ws,
                              size_t ws_size, hipStream_t stream) {
  const float* x = (const float*)d_in[0];
  const float* y = (const float*)d_in[1];
  const float* z = (const float*)d_in[2];
  char* ws = (char*)d_ws;
  ushort* nrm1 = (ushort*)ws;                       // 4096*384 bf16
  ushort* nrm2 = nrm1 + (size_t)BHALF * KCAT;       // 4096*384 bf16
  float* sums = (float*)(ws + 2 * (size_t)BHALF * KCAT * sizeof(ushort));
  float* dxyz = sums + 7 * 4096;                    // 3*4096 fp32

  hipMemsetAsync(sums, 0, 7 * 4096 * sizeof(float), stream);
  norm_diag_kernel<<<3 * BHALF / 4, 256, 0, stream>>>(x, y, z, nrm1, nrm2,
                                                      dxyz);
  gram_fused_kernel<<<dim3(16, 32), 512, 0, stream>>>(nrm1, nrm2, sums);
  loss_kernel<<<1, 1024, 0, stream>>>(sums, dxyz, (float*)d_out);
}

// Round 9
// 106.505 us; speedup vs baseline: 3.8815x; 3.8815x over previous
//
#include <hip/hip_runtime.h>
#include <hip/hip_bf16.h>

// Problem constants
#define BHALF 4096      // B = 8192/2
#define DDIM 128        // feature dim per matrix
#define KCAT 384        // 3*DDIM, packed row width
#define TEMP_INV 10.0f  // 1/TEMP
#define EXP2K 14.426950408889634f  // 10 * log2(e): exp(v*10) = exp2(v*EXP2K)

typedef __attribute__((ext_vector_type(8))) short short8;   // 8 bf16
typedef __attribute__((ext_vector_type(4))) float f32x4;    // 16x16 MFMA acc

// Async global->LDS, 16B per lane. LDS dest is wave-uniform base (HW adds
// lane*16). Global source is per-lane.
__device__ __forceinline__ void gload16(const ushort* g, ushort* l) {
  __builtin_amdgcn_global_load_lds(
      (const __attribute__((address_space(1))) unsigned int*)g,
      (__attribute__((address_space(3))) unsigned int*)l, 16, 0, 0);
}

// ---------------------------------------------------------------------------
// Fused normalize + diag: one wave per (matrix, row-pair i).
__global__ __launch_bounds__(256) void norm_diag_kernel(
    const float* __restrict__ x, const float* __restrict__ y,
    const float* __restrict__ z, ushort* __restrict__ nrm1,
    ushort* __restrict__ nrm2, float* __restrict__ dxyz) {
  int wave = threadIdx.x >> 6;
  int lane = threadIdx.x & 63;
  int gi = blockIdx.x * 4 + wave;  // 0 .. 3*4096-1
  int mat = gi >> 12;
  int i = gi & 4095;
  const float* src = (mat == 0 ? x : (mat == 1 ? y : z));
  float2 a = *(const float2*)(src + (size_t)i * DDIM + lane * 2);
  float2 b = *(const float2*)(src + (size_t)(i + BHALF) * DDIM + lane * 2);
  float s1 = a.x * a.x + a.y * a.y;
  float s2 = b.x * b.x + b.y * b.y;
  float d = a.x * b.x + a.y * b.y;
#pragma unroll
  for (int m = 1; m < 64; m <<= 1) {
    s1 += __shfl_xor(s1, m, 64);
    s2 += __shfl_xor(s2, m, 64);
    d += __shfl_xor(d, m, 64);
  }
  float r1 = 1.0f / fmaxf(sqrtf(s1), 1e-12f);
  float r2 = 1.0f / fmaxf(sqrtf(s2), 1e-12f);
  ushort* d1 = nrm1 + (size_t)i * KCAT + mat * DDIM + lane * 2;
  ushort* d2 = nrm2 + (size_t)i * KCAT + mat * DDIM + lane * 2;
  __hip_bfloat162 o1, o2;
  o1.x = __float2bfloat16(a.x * r1);
  o1.y = __float2bfloat16(a.y * r1);
  o2.x = __float2bfloat16(b.x * r2);
  o2.y = __float2bfloat16(b.y * r2);
  *(__hip_bfloat162*)d1 = o1;
  *(__hip_bfloat162*)d2 = o2;
  if (lane == 0) dxyz[mat * BHALF + i] = d * r1 * r2;
}

// ---------------------------------------------------------------------------
// Fused 4-gram kernel v5: 128x128 tile, 4 waves (2x2, wave tile 64x64),
// 256 threads (escapes the 512-thread 128-VGPR allocator cap seen in
// R5/R6/R8; m97's identical geometry compiled to 164 VGPR, no spill),
// 16x16x32 bf16 MFMA, BK=32, 24 K-steps:
//   t 0-11 : g3^T = mfma(nrm2_frag, nrm1_frag), K=384 (swapped operands so
//            the needed reduction is the cheap lane-local direction)
//   t 12-15: g0 = x1·y1^T   t 16-19: g1 = x1·z1^T   t 20-23: g2 = y1·z1^T
// Double-buffered global_load_lds staging, counted vmcnt(4).
// Flushes go to LDS scratch via ds-atomics (invisible to vmcnt); one
// epilogue pass does ~3.5 global atomics per thread.
// 1024 blocks, ~35.5 KB LDS -> expect 3 blocks/CU resident (m97/m114
// cross-block overlap regime).
// sums layout (4096 floats each): [rs0, cs0, rs1, cs1, rs2, cs2, rs3]
__global__ __launch_bounds__(256) void gram_fused_kernel(
    const ushort* __restrict__ nrm1, const ushort* __restrict__ nrm2,
    float* __restrict__ sums) {
  __shared__ ushort As[2 * 128 * 32];  // 16 KB: buf*4096 + row*32 + col
  __shared__ ushort Bs[2 * 128 * 32];  // 16 KB
  // Flush scratch: [0,128) rs3 | [128,256) rs0 | [256,384) cs0 |
  // [384,512) rs1 | [512,640) cs1 | [640,768) rs2 | [768,896) cs2
  __shared__ float fl[896];

  int tid = threadIdx.x;
  int lane = tid & 63;
  int wave = tid >> 6;  // 0..3
  int wr = wave >> 1;   // 0..1: rows wr*64
  int wc = wave & 1;    // 0..1: cols wc*64

  int rowbase = blockIdx.x * 128;
  int colbase = blockIdx.y * 128;

  for (int i = tid; i < 896; i += 256) fl[i] = 0.0f;

  // Staging: lane l -> row base+(l>>2), 16B chunk (l&3); source chunk
  // pre-swizzled by (l>>3)&3 (R2-verified 0-conflict involution).
  int srow = lane >> 2;
  int swz8 = ((lane & 3) ^ ((lane >> 3) & 3)) << 3;
  const ushort* gA =
      nrm1 + (size_t)(rowbase + wave * 32 + srow) * KCAT + swz8;
  const ushort* gB1 =
      nrm1 + (size_t)(colbase + wave * 32 + srow) * KCAT + swz8;
  const ushort* gB2 =
      nrm2 + (size_t)(colbase + wave * 32 + srow) * KCAT + swz8;

  // Fragment reads (R2-verified): row = grp*16 + rsel, k-chunk = lane>>4,
  // slot = chunk ^ ((rsel>>1)&3).
  int rsel = lane & 15;
  int slot8 = (((lane >> 4) ^ ((rsel >> 1) & 3)) << 3);

  f32x4 acc[4][4] = {};

  // In-LDS flush helpers (ds atomics — never touch vmcnt).
  auto flush_cheap = [&]() {
#pragma unroll
    for (int m = 0; m < 4; ++m) {
      float s = 0.0f;
#pragma unroll
      for (int n = 0; n < 4; ++n)
#pragma unroll
        for (int r = 0; r < 4; ++r) s += exp2f(acc[m][n][r] * EXP2K);
      s += __shfl_xor(s, 16, 64);
      s += __shfl_xor(s, 32, 64);
      if (lane < 16) atomicAdd(&fl[wr * 64 + m * 16 + lane], s);
#pragma unroll
      for (int n = 0; n < 4; ++n)
#pragma unroll
        for (int r = 0; r < 4; ++r) acc[m][n][r] = 0.0f;
    }
  };
  auto flush_full = [&](int roff, int coff) {
#pragma unroll
    for (int m = 0; m < 4; ++m)
#pragma unroll
      for (int n = 0; n < 4; ++n)
#pragma unroll
        for (int r = 0; r < 4; ++r)
          acc[m][n][r] = exp2f(acc[m][n][r] * EXP2K);
    // row sums (reduce over cols: n + xor over lane&15)
#pragma unroll
    for (int m = 0; m < 4; ++m) {
      float rsum[4];
#pragma unroll
      for (int r = 0; r < 4; ++r)
        rsum[r] = acc[m][0][r] + acc[m][1][r] + acc[m][2][r] + acc[m][3][r];
#pragma unroll
      for (int r = 0; r < 4; ++r) {
        rsum[r] += __shfl_xor(rsum[r], 1, 64);
        rsum[r] += __shfl_xor(rsum[r], 2, 64);
        rsum[r] += __shfl_xor(rsum[r], 4, 64);
        rsum[r] += __shfl_xor(rsum[r], 8, 64);
      }
      if ((lane & 15) == 0) {
        int rb = roff + wr * 64 + m * 16 + (lane >> 4) * 4;
#pragma unroll
        for (int r = 0; r < 4; ++r) atomicAdd(&fl[rb + r], rsum[r]);
      }
    }
    // col sums (reduce over rows: m, r, xor16, xor32)
#pragma unroll
    for (int n = 0; n < 4; ++n) {
      float c = 0.0f;
#pragma unroll
      for (int m = 0; m < 4; ++m)
#pragma unroll
        for (int r = 0; r < 4; ++r) c += acc[m][n][r];
      c += __shfl_xor(c, 16, 64);
      c += __shfl_xor(c, 32, 64);
      if (lane < 16) atomicAdd(&fl[coff + wc * 64 + n * 16 + lane], c);
#pragma unroll
      for (int m = 0; m < 4; ++m)
#pragma unroll
        for (int r = 0; r < 4; ++r) acc[m][n][r] = 0.0f;
    }
  };

#define SCHED(t, ao, bp)                                                     \
  do {                                                                       \
    if ((t) < 12)      { ao = (t) * 32;            bp = gB2 + (t) * 32; }    \
    else if ((t) < 16) { ao = ((t)-12) * 32;       bp = gB1 + 128 + ((t)-12) * 32; } \
    else if ((t) < 20) { ao = ((t)-16) * 32;       bp = gB1 + 256 + ((t)-16) * 32; } \
    else               { ao = 128 + ((t)-20) * 32; bp = gB1 + 256 + ((t)-20) * 32; } \
  } while (0)

  // Per wave per step: A 2 loads (16 rows each), B 2 loads.
#define STAGE(b, ao, bp)                                                     \
  do {                                                                       \
    gload16(gA + (ao), &As[(b)*4096 + wave * 1024]);                         \
    gload16(gA + (ao) + (size_t)16 * KCAT, &As[(b)*4096 + wave * 1024 + 512]); \
    gload16((bp), &Bs[(b)*4096 + wave * 1024]);                              \
    gload16((bp) + (size_t)16 * KCAT, &Bs[(b)*4096 + wave * 1024 + 512]);    \
  } while (0)

  {
    int ao; const ushort* bp;
    SCHED(0, ao, bp);
    STAGE(0, ao, bp);
  }

  int buf = 0;
  for (int gt = 0; gt < 24; ++gt) {
    if (gt < 23) {
      int ao; const ushort* bp;
      SCHED(gt + 1, ao, bp);
      STAGE(buf ^ 1, ao, bp);
      // wait only for this step's 4 loads; next step's 4 stay in flight
      asm volatile("s_waitcnt vmcnt(4)" ::: "memory");
    } else {
      asm volatile("s_waitcnt vmcnt(0)" ::: "memory");
    }
    __builtin_amdgcn_s_barrier();
    __builtin_amdgcn_sched_barrier(0);  // no LDS-read hoisting above barrier

    const ushort* A = &As[buf * 4096];
    const ushort* B = &Bs[buf * 4096];
    short8 af[4], bf[4];
#pragma unroll
    for (int m = 0; m < 4; ++m)
      af[m] = *(const short8*)&A[(wr * 64 + m * 16 + rsel) * 32 + slot8];
#pragma unroll
    for (int n = 0; n < 4; ++n)
      bf[n] = *(const short8*)&B[(wc * 64 + n * 16 + rsel) * 32 + slot8];
    if (gt < 12) {
#pragma unroll
      for (int m = 0; m < 4; ++m)
#pragma unroll
        for (int n = 0; n < 4; ++n)
          acc[m][n] = __builtin_amdgcn_mfma_f32_16x16x32_bf16(
              bf[n], af[m], acc[m][n], 0, 0, 0);
    } else {
#pragma unroll
      for (int m = 0; m < 4; ++m)
#pragma unroll
        for (int n = 0; n < 4; ++n)
          acc[m][n] = __builtin_amdgcn_mfma_f32_16x16x32_bf16(
              af[m], bf[n], acc[m][n], 0, 0, 0);
    }
    __builtin_amdgcn_s_barrier();  // buf reads done before its next overwrite

    if (gt == 11) flush_cheap();
    else if (gt == 15) flush_full(128, 256);
    else if (gt == 19) flush_full(384, 512);
    buf ^= 1;
  }
  flush_full(640, 768);
#undef STAGE
#undef SCHED

  // Epilogue: one coalesced global-atomic pass (~3.5 per thread).
  __syncthreads();
  for (int i = tid; i < 896; i += 256) {
    float v = fl[i];
    float* dst;
    if (i < 128)       dst = &sums[6 * 4096 + rowbase + i];
    else if (i < 256)  dst = &sums[rowbase + i - 128];
    else if (i < 384)  dst = &sums[4096 + colbase + i - 256];
    else if (i < 512)  dst = &sums[2 * 4096 + rowbase + i - 384];
    else if (i < 640)  dst = &sums[3 * 4096 + colbase + i - 512];
    else if (i < 768)  dst = &sums[4 * 4096 + rowbase + i - 640];
    else               dst = &sums[5 * 4096 + colbase + i - 768];
    atomicAdd(dst, v);
  }
}

// ---------------------------------------------------------------------------
// Final scalar reduction.
__global__ __launch_bounds__(1024) void loss_kernel(
    const float* __restrict__ sums, const float* __restrict__ dxyz,
    float* __restrict__ out) {
  const float* rs0 = sums;
  const float* cs0 = sums + 4096;
  const float* rs1 = sums + 2 * 4096;
  const float* cs1 = sums + 3 * 4096;
  const float* rs2 = sums + 4 * 4096;
  const float* cs2 = sums + 5 * 4096;
  const float* rs3 = sums + 6 * 4096;
  int tid = threadIdx.x;
  float acc = 0.0f;
  for (int i = tid; i < BHALF; i += 1024) {
    float dxv = dxyz[i];
    float dyv = dxyz[4096 + i];
    float dzv = dxyz[2 * 4096 + i];
    float lx = logf(rs0[i] + rs1[i]) - TEMP_INV * dxv;
    float ly = logf(cs0[i] + rs2[i]) - TEMP_INV * dyv;
    float lz = logf(cs1[i] + cs2[i]) - TEMP_INV * dzv;
    float lv = logf(rs3[i]) - TEMP_INV * (dxv + dyv + dzv);
    acc += lx + ly + lz + lv;
  }
  __shared__ float red[16];
#pragma unroll
  for (int m = 1; m < 64; m <<= 1) acc += __shfl_xor(acc, m, 64);
  if ((tid & 63) == 0) red[tid >> 6] = acc;
  __syncthreads();
  if (tid == 0) {
    float t = 0.0f;
#pragma unroll
    for (int i = 0; i < 16; ++i) t += red[i];
    out[0] = t * (1.0f / 4096.0f);
  }
}

// ---------------------------------------------------------------------------
extern "C" void kernel_launch(void* const* d_in, const int* in_sizes, int n_in,
                              void* d_out, int out_size, void* d_ws,
                              size_t ws_size, hipStream_t stream) {
  const float* x = (const float*)d_in[0];
  const float* y = (const float*)d_in[1];
  const float* z = (const float*)d_in[2];
  char* ws = (char*)d_ws;
  ushort* nrm1 = (ushort*)ws;                       // 4096*384 bf16
  ushort* nrm2 = nrm1 + (size_t)BHALF * KCAT;       // 4096*384 bf16
  float* sums = (float*)(ws + 2 * (size_t)BHALF * KCAT * sizeof(ushort));
  float* dxyz = sums + 7 * 4096;                    // 3*4096 fp32

  hipMemsetAsync(sums, 0, 7 * 4096 * sizeof(float), stream);
  norm_diag_kernel<<<3 * BHALF / 4, 256, 0, stream>>>(x, y, z, nrm1, nrm2,
                                                      dxyz);
  gram_fused_kernel<<<dim3(32, 32), 256, 0, stream>>>(nrm1, nrm2, sums);
  loss_kernel<<<1, 1024, 0, stream>>>(sums, dxyz, (float*)d_out);
}

// Round 10
// 76.948 us; speedup vs baseline: 5.3724x; 1.3841x over previous
//
#include <hip/hip_runtime.h>
#include <hip/hip_bf16.h>

// Problem constants
#define BHALF 4096      // B = 8192/2
#define DDIM 128        // feature dim per matrix
#define KCAT 384        // 3*DDIM, packed row width
#define TEMP_INV 10.0f  // 1/TEMP
#define EXP2K 14.426950408889634f  // 10 * log2(e): exp(v*10) = exp2(v*EXP2K)

typedef __attribute__((ext_vector_type(8))) short short8;   // 8 bf16
typedef __attribute__((ext_vector_type(4))) float f32x4;    // 16x16 MFMA acc

// Async global->LDS, 16B per lane. LDS dest is wave-uniform base (HW adds
// lane*16). Global source is per-lane.
__device__ __forceinline__ void gload16(const ushort* g, ushort* l) {
  __builtin_amdgcn_global_load_lds(
      (const __attribute__((address_space(1))) unsigned int*)g,
      (__attribute__((address_space(3))) unsigned int*)l, 16, 0, 0);
}

// ---------------------------------------------------------------------------
// Fused normalize + diag: one wave per (matrix, row-pair i).
__global__ __launch_bounds__(256) void norm_diag_kernel(
    const float* __restrict__ x, const float* __restrict__ y,
    const float* __restrict__ z, ushort* __restrict__ nrm1,
    ushort* __restrict__ nrm2, float* __restrict__ dxyz) {
  int wave = threadIdx.x >> 6;
  int lane = threadIdx.x & 63;
  int gi = blockIdx.x * 4 + wave;  // 0 .. 3*4096-1
  int mat = gi >> 12;
  int i = gi & 4095;
  const float* src = (mat == 0 ? x : (mat == 1 ? y : z));
  float2 a = *(const float2*)(src + (size_t)i * DDIM + lane * 2);
  float2 b = *(const float2*)(src + (size_t)(i + BHALF) * DDIM + lane * 2);
  float s1 = a.x * a.x + a.y * a.y;
  float s2 = b.x * b.x + b.y * b.y;
  float d = a.x * b.x + a.y * b.y;
#pragma unroll
  for (int m = 1; m < 64; m <<= 1) {
    s1 += __shfl_xor(s1, m, 64);
    s2 += __shfl_xor(s2, m, 64);
    d += __shfl_xor(d, m, 64);
  }
  float r1 = 1.0f / fmaxf(sqrtf(s1), 1e-12f);
  float r2 = 1.0f / fmaxf(sqrtf(s2), 1e-12f);
  ushort* d1 = nrm1 + (size_t)i * KCAT + mat * DDIM + lane * 2;
  ushort* d2 = nrm2 + (size_t)i * KCAT + mat * DDIM + lane * 2;
  __hip_bfloat162 o1, o2;
  o1.x = __float2bfloat16(a.x * r1);
  o1.y = __float2bfloat16(a.y * r1);
  o2.x = __float2bfloat16(b.x * r2);
  o2.y = __float2bfloat16(b.y * r2);
  *(__hip_bfloat162*)d1 = o1;
  *(__hip_bfloat162*)d2 = o2;
  if (lane == 0) dxyz[mat * BHALF + i] = d * r1 * r2;
}

// ---------------------------------------------------------------------------
// Flush helpers (R1/R2-verified, global atomics, called once per block).
// 16x16 C/D layout: col = lane&15, row = (lane>>4)*4 + r.

// g3^T (operand-swapped mfma(b,a)): D[j][i]; reduce over j = regs + xor16 +
// xor32; one value per i (nrm1 row). Verified R7/R9.
__device__ __forceinline__ void flush_cheap(f32x4 (&acc)[4][4],
                                            float* __restrict__ dst, int base,
                                            int lane) {
#pragma unroll
  for (int m = 0; m < 4; ++m) {
    float s = 0.0f;
#pragma unroll
    for (int n = 0; n < 4; ++n)
#pragma unroll
      for (int r = 0; r < 4; ++r) s += exp2f(acc[m][n][r] * EXP2K);
    s += __shfl_xor(s, 16, 64);
    s += __shfl_xor(s, 32, 64);
    if (lane < 16) atomicAdd(&dst[base + m * 16 + lane], s);
  }
}

// Full flush: D[i][j]; rs[i] += sum_j exp, cs[j] += sum_i exp. Verified R1/R2.
__device__ __forceinline__ void flush_full(f32x4 (&acc)[4][4],
                                           float* __restrict__ rs,
                                           float* __restrict__ cs, int rbase,
                                           int cbase, int lane) {
#pragma unroll
  for (int m = 0; m < 4; ++m)
#pragma unroll
    for (int n = 0; n < 4; ++n)
#pragma unroll
      for (int r = 0; r < 4; ++r)
        acc[m][n][r] = exp2f(acc[m][n][r] * EXP2K);

  // row sums: reduce over cols (n + xor over lane&15)
#pragma unroll
  for (int m = 0; m < 4; ++m) {
    float rsum[4];
#pragma unroll
    for (int r = 0; r < 4; ++r)
      rsum[r] = acc[m][0][r] + acc[m][1][r] + acc[m][2][r] + acc[m][3][r];
#pragma unroll
    for (int r = 0; r < 4; ++r) {
      rsum[r] += __shfl_xor(rsum[r], 1, 64);
      rsum[r] += __shfl_xor(rsum[r], 2, 64);
      rsum[r] += __shfl_xor(rsum[r], 4, 64);
      rsum[r] += __shfl_xor(rsum[r], 8, 64);
    }
    if ((lane & 15) == 0) {
      int rb = rbase + m * 16 + (lane >> 4) * 4;
#pragma unroll
      for (int r = 0; r < 4; ++r) atomicAdd(&rs[rb + r], rsum[r]);
    }
  }

  // col sums: reduce over rows (m, r, xor16, xor32)
#pragma unroll
  for (int n = 0; n < 4; ++n) {
    float csum = 0.0f;
#pragma unroll
    for (int m = 0; m < 4; ++m)
#pragma unroll
      for (int r = 0; r < 4; ++r) csum += acc[m][n][r];
    csum += __shfl_xor(csum, 16, 64);
    csum += __shfl_xor(csum, 32, 64);
    if (lane < 16) atomicAdd(&cs[cbase + n * 16 + lane], csum);
  }
}

// ---------------------------------------------------------------------------
// Gram kernel v6 "big slab": 128x128 tile, 4 waves (2x2, wave tile 64x64),
// 256 threads, 16x16x32 bf16 MFMA, BK=128: the WHOLE gram K staged in one
// slab -> ONE vmcnt(0)+barrier per slab, then 64 uninterrupted MFMAs/wave.
//   z-remapped gram g: g3 (K=384, 3 slabs, operand-swapped) dispatched
//   FIRST for tail balance; g0 x1·y1^T, g1 x1·z1^T, g2 y1·z1^T (1 slab).
// LDS: As/Bs [kslice 4][row 128][32 ushort] = 32 KB each, 64 KB total ->
// 2 blocks/CU resident; 4096 independent blocks (16/CU of work) so the
// co-resident block's MFMA burst hides this block's stage drain (m114).
// Staging/fragment swizzle: R2-verified involution (0 measured conflicts):
// physical chunk = logical ^ ((row mod 16)>>1)&3 on both source and read.
// Flush: once per block, global atomics (after all vmcnt waits -> no
// pipeline coupling, the R7 lesson).
// sums layout (4096 floats each): [rs0, cs0, rs1, cs1, rs2, cs2, rs3]
__global__ __launch_bounds__(256) void gram_slab_kernel(
    const ushort* __restrict__ nrm1, const ushort* __restrict__ nrm2,
    float* __restrict__ sums) {
  __shared__ ushort As[4][128][32];  // 32 KB, kslice-major
  __shared__ ushort Bs[4][128][32];  // 32 KB

  int tid = threadIdx.x;
  int lane = tid & 63;
  int wave = tid >> 6;  // 0..3
  int wr = wave >> 1;   // 0..1: rows wr*64
  int wc = wave & 1;    // 0..1: cols wc*64
  int g = (blockIdx.z == 0) ? 3 : (int)blockIdx.z - 1;  // heavy g3 first
  int rowbase = blockIdx.x * 128;
  int colbase = blockIdx.y * 128;

  const ushort* Ab;
  const ushort* Bb;
  int nslab;
  float* rs;
  float* cs;
  if (g == 3) {
    Ab = nrm1;       Bb = nrm2;       nslab = 3;
    rs = sums + 6 * 4096; cs = nullptr;
  } else if (g == 0) {
    Ab = nrm1;       Bb = nrm1 + 128; nslab = 1;
    rs = sums;            cs = sums + 4096;
  } else if (g == 1) {
    Ab = nrm1;       Bb = nrm1 + 256; nslab = 1;
    rs = sums + 2 * 4096; cs = sums + 3 * 4096;
  } else {
    Ab = nrm1 + 128; Bb = nrm1 + 256; nslab = 1;
    rs = sums + 4 * 4096; cs = sums + 5 * 4096;
  }

  // Staging: lane l -> LDS row +(l>>2) (16 rows/load), chunk (l&3); source
  // chunk pre-swizzled by ((l>>3)&3) = ((row mod 16)>>1)&3.
  int srow = lane >> 2;
  int schunk = ((lane & 3) ^ ((lane >> 3) & 3)) << 3;
  const ushort* gA =
      Ab + (size_t)(rowbase + wave * 32 + srow) * KCAT + schunk;
  const ushort* gB =
      Bb + (size_t)(colbase + wave * 32 + srow) * KCAT + schunk;

  // Fragment reads: row = grp*16 + rsel, logical chunk = lane>>4,
  // physical slot = chunk ^ ((rsel>>1)&3).
  int rsel = lane & 15;
  int slot8 = (((lane >> 4) ^ ((rsel >> 1) & 3)) << 3);

  f32x4 acc[4][4] = {};

  for (int slab = 0; slab < nslab; ++slab) {
    if (slab) {
      __builtin_amdgcn_s_barrier();       // prev slab reads done everywhere
      __builtin_amdgcn_sched_barrier(0);  // keep stage below the barrier
    }
    int k0 = slab * 128;
    // 16 loads/wave: A rows [wave*32,+32) x 4 kslices, B likewise.
#pragma unroll
    for (int s = 0; s < 4; ++s) {
#pragma unroll
      for (int rg = 0; rg < 2; ++rg) {
        gload16(gA + k0 + s * 32 + (size_t)rg * 16 * KCAT,
                &As[s][wave * 32 + rg * 16][0]);
        gload16(gB + k0 + s * 32 + (size_t)rg * 16 * KCAT,
                &Bs[s][wave * 32 + rg * 16][0]);
      }
    }
    asm volatile("s_waitcnt vmcnt(0)" ::: "memory");
    __builtin_amdgcn_s_barrier();
    __builtin_amdgcn_sched_barrier(0);  // no LDS-read hoisting above barrier

    if (g == 3) {
#pragma unroll
      for (int kk = 0; kk < 4; ++kk) {
        short8 af[4], bf[4];
#pragma unroll
        for (int m = 0; m < 4; ++m)
          af[m] = *(const short8*)&As[kk][wr * 64 + m * 16 + rsel][slot8];
#pragma unroll
        for (int n = 0; n < 4; ++n)
          bf[n] = *(const short8*)&Bs[kk][wc * 64 + n * 16 + rsel][slot8];
#pragma unroll
        for (int m = 0; m < 4; ++m)
#pragma unroll
          for (int n = 0; n < 4; ++n)
            acc[m][n] = __builtin_amdgcn_mfma_f32_16x16x32_bf16(
                bf[n], af[m], acc[m][n], 0, 0, 0);
      }
    } else {
#pragma unroll
      for (int kk = 0; kk < 4; ++kk) {
        short8 af[4], bf[4];
#pragma unroll
        for (int m = 0; m < 4; ++m)
          af[m] = *(const short8*)&As[kk][wr * 64 + m * 16 + rsel][slot8];
#pragma unroll
        for (int n = 0; n < 4; ++n)
          bf[n] = *(const short8*)&Bs[kk][wc * 64 + n * 16 + rsel][slot8];
#pragma unroll
        for (int m = 0; m < 4; ++m)
#pragma unroll
          for (int n = 0; n < 4; ++n)
            acc[m][n] = __builtin_amdgcn_mfma_f32_16x16x32_bf16(
                af[m], bf[n], acc[m][n], 0, 0, 0);
      }
    }
  }

  // One flush per block; acc is register-only, no barrier needed.
  if (g == 3)
    flush_cheap(acc, rs, rowbase + wr * 64, lane);
  else
    flush_full(acc, rs, cs, rowbase + wr * 64, colbase + wc * 64, lane);
}

// ---------------------------------------------------------------------------
// Final scalar reduction.
__global__ __launch_bounds__(1024) void loss_kernel(
    const float* __restrict__ sums, const float* __restrict__ dxyz,
    float* __restrict__ out) {
  const float* rs0 = sums;
  const float* cs0 = sums + 4096;
  const float* rs1 = sums + 2 * 4096;
  const float* cs1 = sums + 3 * 4096;
  const float* rs2 = sums + 4 * 4096;
  const float* cs2 = sums + 5 * 4096;
  const float* rs3 = sums + 6 * 4096;
  int tid = threadIdx.x;
  float acc = 0.0f;
  for (int i = tid; i < BHALF; i += 1024) {
    float dxv = dxyz[i];
    float dyv = dxyz[4096 + i];
    float dzv = dxyz[2 * 4096 + i];
    float lx = logf(rs0[i] + rs1[i]) - TEMP_INV * dxv;
    float ly = logf(cs0[i] + rs2[i]) - TEMP_INV * dyv;
    float lz = logf(cs1[i] + cs2[i]) - TEMP_INV * dzv;
    float lv = logf(rs3[i]) - TEMP_INV * (dxv + dyv + dzv);
    acc += lx + ly + lz + lv;
  }
  __shared__ float red[16];
#pragma unroll
  for (int m = 1; m < 64; m <<= 1) acc += __shfl_xor(acc, m, 64);
  if ((tid & 63) == 0) red[tid >> 6] = acc;
  __syncthreads();
  if (tid == 0) {
    float t = 0.0f;
#pragma unroll
    for (int i = 0; i < 16; ++i) t += red[i];
    out[0] = t * (1.0f / 4096.0f);
  }
}

// ---------------------------------------------------------------------------
extern "C" void kernel_launch(void* const* d_in, const int* in_sizes, int n_in,
                              void* d_out, int out_size, void* d_ws,
                              size_t ws_size, hipStream_t stream) {
  const float* x = (const float*)d_in[0];
  const float* y = (const float*)d_in[1];
  const float* z = (const float*)d_in[2];
  char* ws = (char*)d_ws;
  ushort* nrm1 = (ushort*)ws;                       // 4096*384 bf16
  ushort* nrm2 = nrm1 + (size_t)BHALF * KCAT;       // 4096*384 bf16
  float* sums = (float*)(ws + 2 * (size_t)BHALF * KCAT * sizeof(ushort));
  float* dxyz = sums + 7 * 4096;                    // 3*4096 fp32

  hipMemsetAsync(sums, 0, 7 * 4096 * sizeof(float), stream);
  norm_diag_kernel<<<3 * BHALF / 4, 256, 0, stream>>>(x, y, z, nrm1, nrm2,
                                                      dxyz);
  gram_slab_kernel<<<dim3(32, 32, 4), 256, 0, stream>>>(nrm1, nrm2, sums);
  loss_kernel<<<1, 1024, 0, stream>>>(sums, dxyz, (float*)d_out);
}